// Round 1
// baseline (1997.305 us; speedup 1.0000x reference)
//
#include <hip/hip_runtime.h>
#include <hip/hip_bf16.h>
#include <math.h>

// ---------------- constants ----------------
constexpr int BB = 256;        // batch
constexpr int NCLS = 10;
constexpr int NROUTE = 1152;   // 32*6*6

// ---------------- conv1: x[256,1,28,28] -> h[256,256,20,20], relu ----------------
__global__ __launch_bounds__(256) void k_conv1(const float* __restrict__ x,
                                               const float* __restrict__ w,
                                               const float* __restrict__ bias,
                                               float* __restrict__ h) {
  int b = blockIdx.x >> 5, ocg = blockIdx.x & 31;   // 8 oc per block
  __shared__ float sx[28 * 36];
  __shared__ float sw[8 * 81];
  int tid = threadIdx.x;
  for (int i = tid; i < 28 * 28; i += 256) {
    int r = i / 28, c = i - r * 28;
    sx[r * 36 + c] = x[b * 784 + i];
  }
  for (int i = tid; i < 8 * 81; i += 256) sw[i] = w[(ocg * 8) * 81 + i];
  __syncthreads();
  for (int q = tid; q < 800; q += 256) {        // 8 oc * 100 spatial-quads
    int oc8 = q / 100;
    int s4 = (q - oc8 * 100) * 4;
    int oy = s4 / 20, ox = s4 - oy * 20;
    float bv = bias[ocg * 8 + oc8];
    float acc0 = bv, acc1 = bv, acc2 = bv, acc3 = bv;
    const float* wr = &sw[oc8 * 81];
#pragma unroll
    for (int ky = 0; ky < 9; ++ky) {
      const float* xr = &sx[(oy + ky) * 36 + ox];
      float4 a0 = *(const float4*)(xr);
      float4 a1 = *(const float4*)(xr + 4);
      float4 a2 = *(const float4*)(xr + 8);
      float a[12] = {a0.x, a0.y, a0.z, a0.w, a1.x, a1.y, a1.z, a1.w,
                     a2.x, a2.y, a2.z, a2.w};
#pragma unroll
      for (int kx = 0; kx < 9; ++kx) {
        float wv = wr[ky * 9 + kx];
        acc0 += a[kx] * wv;
        acc1 += a[kx + 1] * wv;
        acc2 += a[kx + 2] * wv;
        acc3 += a[kx + 3] * wv;
      }
    }
    float* op = &h[(size_t)(b * 256 + ocg * 8 + oc8) * 400 + s4];
    op[0] = fmaxf(acc0, 0.f);
    op[1] = fmaxf(acc1, 0.f);
    op[2] = fmaxf(acc2, 0.f);
    op[3] = fmaxf(acc3, 0.f);
  }
}

// ------- primary caps conv: h[256,256,20,20] -> p[256,256,6,6], stride 2 -------
// implicit GEMM: rows = (batch,spatial) 144/block (4 b x 36 s), cols = 64 oc,
// K = 256 ic * 81 taps, split-K=2 (kb writes its own partial buffer).
constexpr int ICCH = 2;
__global__ __launch_bounds__(256) void k_prim(const float* __restrict__ h,
                                              const float* __restrict__ w,
                                              float* __restrict__ pout) {
  int g = blockIdx.x & 63;            // row group: batches 4g..4g+3
  int t = (blockIdx.x >> 6) & 3;      // oc tile: 64t..
  int kb = blockIdx.x >> 8;           // split-K half
  int b0 = g * 4, oc0 = t * 64;
  __shared__ float sh[ICCH][4][408];  // ic, batch, 20x20 plane (padded)
  __shared__ float sw[162][68];       // k within chunk, oc (padded)
  int tid = threadIdx.x;
  int ty = tid >> 4, tx = tid & 15;
  int bp = ty >> 2;                   // batch-in-group
  int s0 = (ty & 3) * 9;              // first spatial index of this thread
  int aoff[9];
#pragma unroll
  for (int m = 0; m < 9; ++m) {
    int s = s0 + m;
    aoff[m] = (s / 6) * 40 + (s % 6) * 2;
  }
  float acc[9][4];
#pragma unroll
  for (int m = 0; m < 9; ++m)
#pragma unroll
    for (int n = 0; n < 4; ++n) acc[m][n] = 0.f;

  for (int chunk = 0; chunk < 64; ++chunk) {
    int ic0 = kb * 128 + chunk * ICCH;
    __syncthreads();
    // stage h planes: 2 ic * 4 b * 100 float4
    for (int idx = tid; idx < 800; idx += 256) {
      int icc = idx / 400;
      int rem = idx - icc * 400;
      int bq = rem / 100;
      int p4 = rem - bq * 100;
      float4 v = *(const float4*)&h[(size_t)((b0 + bq) * 256 + ic0 + icc) * 400 + p4 * 4];
      *(float4*)&sh[icc][bq][p4 * 4] = v;
    }
    // stage weights transposed: sw[kk][oc']
    for (int idx = tid; idx < 162 * 64; idx += 256) {
      int ocp = idx / 162;
      int kk = idx - ocp * 162;
      sw[kk][ocp] = w[(size_t)(oc0 + ocp) * 20736 + ic0 * 81 + kk];
    }
    __syncthreads();
#pragma unroll
    for (int icc = 0; icc < ICCH; ++icc) {
      const float* A = sh[icc][bp];
      for (int ky = 0; ky < 9; ++ky) {
#pragma unroll
        for (int kx = 0; kx < 9; ++kx) {
          int kk = icc * 81 + ky * 9 + kx;
          float4 wv = *(const float4*)&sw[kk][tx * 4];
          int ab = ky * 20 + kx;
          float a[9];
#pragma unroll
          for (int m = 0; m < 9; ++m) a[m] = A[ab + aoff[m]];
#pragma unroll
          for (int m = 0; m < 9; ++m) {
            acc[m][0] += a[m] * wv.x;
            acc[m][1] += a[m] * wv.y;
            acc[m][2] += a[m] * wv.z;
            acc[m][3] += a[m] * wv.w;
          }
        }
      }
    }
  }
  float* pb = pout + (size_t)kb * (BB * 256 * 36);
#pragma unroll
  for (int m = 0; m < 9; ++m) {
    int s = s0 + m;
#pragma unroll
    for (int n = 0; n < 4; ++n) {
      int oc = oc0 + tx * 4 + n;
      pb[(size_t)((b0 + bp) * 256 + oc) * 36 + s] = acc[m][n];
    }
  }
}

// ---- squash: combine split-K partials + bias, reshape to ps[b][r][8], squash over 8 ----
__global__ __launch_bounds__(256) void k_squash(const float* __restrict__ p0,
                                                const float* __restrict__ p1,
                                                const float* __restrict__ bias,
                                                float* __restrict__ ps) {
  int idx = blockIdx.x * 256 + threadIdx.x;  // (b, r)
  if (idx >= BB * NROUTE) return;
  int b = idx / NROUTE, r = idx - b * NROUTE;
  int c32 = r / 36;
  float v[8];
  float sq = 0.f;
#pragma unroll
  for (int i = 0; i < 8; ++i) {
    size_t off = (size_t)b * 9216 + i * 1152 + r;  // (i*32+c32)*36+s == i*1152+r
    float tt = p0[off] + p1[off] + bias[i * 32 + c32];
    v[i] = tt;
    sq += tt * tt;
  }
  float sc = sqrtf(sq) / (1.f + sq);
  float4 o0 = {v[0] * sc, v[1] * sc, v[2] * sc, v[3] * sc};
  float4 o1 = {v[4] * sc, v[5] * sc, v[6] * sc, v[7] * sc};
  float4* op = (float4*)&ps[(size_t)idx * 8];
  op[0] = o0;
  op[1] = o1;
}

// ---- fused routing: one block per (class c, batch b); priors kept in LDS ----
__global__ __launch_bounds__(256) void k_route(const float* __restrict__ ps,
                                               const float* __restrict__ rw,
                                               float* __restrict__ vout) {
  int c = blockIdx.x / BB;
  int b = blockIdx.x - c * BB;
  __shared__ float pri[16 * NROUTE];  // [o][r] layout, conflict-free
  __shared__ float lg[NROUTE];
  __shared__ float red[64];
  __shared__ float wred[4];
  __shared__ float sca[1];
  __shared__ float vsq[16];
  int tid = threadIdx.x;

  // priors[r][o] = sum_i ps[b,r,i] * rw[c,r,i,o]
  for (int r = tid; r < NROUTE; r += 256) {
    const float4* pp = (const float4*)&ps[(size_t)(b * NROUTE + r) * 8];
    float4 pa = pp[0], pb4 = pp[1];
    float p8[8] = {pa.x, pa.y, pa.z, pa.w, pb4.x, pb4.y, pb4.z, pb4.w};
    const float* wp = &rw[(size_t)(c * NROUTE + r) * 128];
    float pr[16];
#pragma unroll
    for (int o = 0; o < 16; ++o) pr[o] = 0.f;
#pragma unroll
    for (int i = 0; i < 8; ++i) {
      float pv = p8[i];
#pragma unroll
      for (int o = 0; o < 16; ++o) pr[o] += pv * wp[i * 16 + o];
    }
#pragma unroll
    for (int o = 0; o < 16; ++o) pri[o * NROUTE + r] = pr[o];
    lg[r] = 0.f;
  }
  __syncthreads();

  for (int it = 0; it < 3; ++it) {
    // softmax over r: max
    float mx = -1e30f;
    for (int r = tid; r < NROUTE; r += 256) mx = fmaxf(mx, lg[r]);
#pragma unroll
    for (int off = 32; off; off >>= 1) mx = fmaxf(mx, __shfl_xor(mx, off));
    __syncthreads();
    if ((tid & 63) == 0) wred[tid >> 6] = mx;
    __syncthreads();
    mx = fmaxf(fmaxf(wred[0], wred[1]), fmaxf(wred[2], wred[3]));
    // sum of exp
    float sm = 0.f;
    for (int r = tid; r < NROUTE; r += 256) sm += expf(lg[r] - mx);
#pragma unroll
    for (int off = 32; off; off >>= 1) sm += __shfl_xor(sm, off);
    __syncthreads();
    if ((tid & 63) == 0) wred[tid >> 6] = sm;
    __syncthreads();
    float inv = 1.f / (wred[0] + wred[1] + wred[2] + wred[3]);
    // outputs[o] = sum_r probs[r]*priors[r][o]
    float a16[16];
#pragma unroll
    for (int o = 0; o < 16; ++o) a16[o] = 0.f;
    for (int r = tid; r < NROUTE; r += 256) {
      float pr_ = expf(lg[r] - mx) * inv;
#pragma unroll
      for (int o = 0; o < 16; ++o) a16[o] += pr_ * pri[o * NROUTE + r];
    }
#pragma unroll
    for (int o = 0; o < 16; ++o) {
#pragma unroll
      for (int off = 32; off; off >>= 1) a16[o] += __shfl_xor(a16[o], off);
    }
    __syncthreads();
    if ((tid & 63) == 0) {
#pragma unroll
      for (int o = 0; o < 16; ++o) red[(tid >> 6) * 16 + o] = a16[o];
    }
    __syncthreads();
    if (tid < 16) {
      float s = red[tid] + red[16 + tid] + red[32 + tid] + red[48 + tid];
      red[tid] = s;
    }
    __syncthreads();
    if (tid == 0) {
      float sq = 0.f;
      for (int o = 0; o < 16; ++o) sq += red[o] * red[o];
      sca[0] = sqrtf(sq) / (1.f + sq);
    }
    __syncthreads();
    if (tid < 16) vsq[tid] = red[tid] * sca[0];
    __syncthreads();
    if (it < 2) {
      for (int r = tid; r < NROUTE; r += 256) {
        float d = 0.f;
#pragma unroll
        for (int o = 0; o < 16; ++o) d += pri[o * NROUTE + r] * vsq[o];
        lg[r] += d;
      }
      __syncthreads();
    }
  }
  if (tid < 16) vout[(size_t)(c * BB + b) * 16 + tid] = vsq[tid];
}

// ---- classes (softmax of norms) + argmax one-hot mask ----
__global__ __launch_bounds__(64) void k_cls(const float* __restrict__ v,
                                            float* __restrict__ classes,
                                            float* __restrict__ masked) {
  int b = blockIdx.x;
  int t = threadIdx.x;
  __shared__ float snrm[10];
  __shared__ int samax;
  float vv[16];
  if (t < 10) {
    float sq = 0.f;
#pragma unroll
    for (int o = 0; o < 16; ++o) {
      float xx = v[(size_t)(t * BB + b) * 16 + o];
      vv[o] = xx;
      sq += xx * xx;
    }
    snrm[t] = sqrtf(sq);
  }
  __syncthreads();
  if (t == 0) {
    int am = 0;
    float bm = snrm[0];
    for (int cc = 1; cc < 10; ++cc)
      if (snrm[cc] > bm) { bm = snrm[cc]; am = cc; }
    samax = am;
  }
  __syncthreads();
  if (t < 10) {
    float mx = snrm[0];
    for (int cc = 1; cc < 10; ++cc) mx = fmaxf(mx, snrm[cc]);
    float sm = 0.f;
    for (int cc = 0; cc < 10; ++cc) sm += expf(snrm[cc] - mx);
    classes[b * 10 + t] = expf(snrm[t] - mx) / sm;
    float keep = (t == samax) ? 1.f : 0.f;
#pragma unroll
    for (int o = 0; o < 16; ++o)
      masked[(size_t)b * 160 + t * 16 + o] = vv[o] * keep;
  }
}

// ---- small FC GEMM: O[M,N] = act(A[M,K] @ W[K,N] + bias) ----
template <int ACT>  // 0 = relu, 1 = sigmoid
__global__ __launch_bounds__(256) void k_fc(const float* __restrict__ A,
                                            const float* __restrict__ W,
                                            const float* __restrict__ bias,
                                            float* __restrict__ O, int M, int N,
                                            int K) {
  int n0 = blockIdx.x * 64, m0 = blockIdx.y * 64;
  __shared__ float sa[64][17];
  __shared__ float sb[16][64];
  int tid = threadIdx.x, ty = tid >> 4, tx = tid & 15;
  float acc[4][4] = {};
  for (int k0 = 0; k0 < K; k0 += 16) {
    __syncthreads();
    for (int i = tid; i < 64 * 16; i += 256) {
      int m = i >> 4, k = i & 15;
      sa[m][k] = A[(size_t)(m0 + m) * K + k0 + k];
    }
    for (int i = tid; i < 16 * 64; i += 256) {
      int k = i >> 6, n = i & 63;
      int nn = n0 + n;
      sb[k][n] = (nn < N) ? W[(size_t)(k0 + k) * N + nn] : 0.f;
    }
    __syncthreads();
#pragma unroll
    for (int k = 0; k < 16; ++k) {
      float a0 = sa[ty * 4 + 0][k];
      float a1 = sa[ty * 4 + 1][k];
      float a2 = sa[ty * 4 + 2][k];
      float a3 = sa[ty * 4 + 3][k];
      float4 bv = *(const float4*)&sb[k][tx * 4];
      acc[0][0] += a0 * bv.x; acc[0][1] += a0 * bv.y; acc[0][2] += a0 * bv.z; acc[0][3] += a0 * bv.w;
      acc[1][0] += a1 * bv.x; acc[1][1] += a1 * bv.y; acc[1][2] += a1 * bv.z; acc[1][3] += a1 * bv.w;
      acc[2][0] += a2 * bv.x; acc[2][1] += a2 * bv.y; acc[2][2] += a2 * bv.z; acc[2][3] += a2 * bv.w;
      acc[3][0] += a3 * bv.x; acc[3][1] += a3 * bv.y; acc[3][2] += a3 * bv.z; acc[3][3] += a3 * bv.w;
    }
  }
#pragma unroll
  for (int i = 0; i < 4; ++i) {
    int m = m0 + ty * 4 + i;
#pragma unroll
    for (int j = 0; j < 4; ++j) {
      int n = n0 + tx * 4 + j;
      if (n < N) {
        float xv = acc[i][j] + bias[n];
        if (ACT == 0)
          xv = fmaxf(xv, 0.f);
        else
          xv = 1.f / (1.f + expf(-xv));
        O[(size_t)m * N + n] = xv;
      }
    }
  }
}

extern "C" void kernel_launch(void* const* d_in, const int* in_sizes, int n_in,
                              void* d_out, int out_size, void* d_ws,
                              size_t ws_size, hipStream_t stream) {
  (void)in_sizes; (void)n_in; (void)out_size; (void)ws_size;
  const float* x       = (const float*)d_in[0];
  const float* conv1_w = (const float*)d_in[1];
  const float* conv1_b = (const float*)d_in[2];
  const float* prim_w  = (const float*)d_in[3];
  const float* prim_b  = (const float*)d_in[4];
  const float* route_w = (const float*)d_in[5];
  const float* dec_w1  = (const float*)d_in[6];
  const float* dec_b1  = (const float*)d_in[7];
  const float* dec_w2  = (const float*)d_in[8];
  const float* dec_b2  = (const float*)d_in[9];
  const float* dec_w3  = (const float*)d_in[10];
  const float* dec_b3  = (const float*)d_in[11];
  float* out = (float*)d_out;

  float* ws = (float*)d_ws;
  float* h  = ws;                    // 26,214,400 f
  float* p0 = h + 26214400;          // 2,359,296 f  (split-K partial 0; partial 1 follows)
  float* p1 = p0 + 2359296;
  float* ps = p1 + 2359296;          // 2,359,296 f squashed [b][r][8]
  float* v  = ps + 2359296;          // 40,960 f [c][b][16]
  float* mk = v + 40960;             // 40,960 f [b][160]
  float* h1 = mk + 40960;            // 131,072 f
  float* h2 = h1 + 131072;           // 262,144 f

  k_conv1<<<256 * 32, 256, 0, stream>>>(x, conv1_w, conv1_b, h);
  k_prim<<<512, 256, 0, stream>>>(h, prim_w, p0);
  k_squash<<<BB * NROUTE / 256, 256, 0, stream>>>(p0, p1, prim_b, ps);
  k_route<<<NCLS * BB, 256, 0, stream>>>(ps, route_w, v);
  k_cls<<<BB, 64, 0, stream>>>(v, out, mk);
  k_fc<0><<<dim3(8, 4), 256, 0, stream>>>(mk, dec_w1, dec_b1, h1, 256, 512, 160);
  k_fc<0><<<dim3(16, 4), 256, 0, stream>>>(h1, dec_w2, dec_b2, h2, 256, 1024, 512);
  k_fc<1><<<dim3(13, 4), 256, 0, stream>>>(h2, dec_w3, dec_b3, out + 2560, 256, 784, 1024);
}

// Round 2
// 1101.103 us; speedup vs baseline: 1.8139x; 1.8139x over previous
//
#include <hip/hip_runtime.h>
#include <hip/hip_bf16.h>
#include <math.h>

constexpr int BB = 256;
constexpr int NCLS = 10;
constexpr int NROUTE = 1152;

typedef __attribute__((ext_vector_type(8))) short s16x8;
typedef __attribute__((ext_vector_type(4))) float f32x4;

__device__ __forceinline__ void gl16(const void* g, void* l) {
  __builtin_amdgcn_global_load_lds(
      (const __attribute__((address_space(1))) void*)g,
      (__attribute__((address_space(3))) void*)l, 16, 0, 0);
}

// ---- conv1: x[256,1,28,28] -> hT[b_l][y][x][oc] bf16 hi/lo (NHWC), relu ----
__global__ __launch_bounds__(256) void k_conv1b(const float* __restrict__ x,
    const float* __restrict__ w, const float* __restrict__ bias,
    __hip_bfloat16* __restrict__ hT_hi, __hip_bfloat16* __restrict__ hT_lo,
    int b0) {
  int b_l = blockIdx.x >> 2, q = blockIdx.x & 3;
  __shared__ float sx[784];
  __shared__ float sw[64 * 81];
  int t = threadIdx.x;
  for (int i = t; i < 784; i += 256) sx[i] = x[(size_t)(b0 + b_l) * 784 + i];
  for (int i = t; i < 5184; i += 256) sw[i] = w[(size_t)q * 5184 + i];
  __syncthreads();
  int oc = q * 64 + (t & 63);
  int wv = t >> 6;
  float wreg[81];
#pragma unroll
  for (int k = 0; k < 81; ++k) wreg[k] = sw[(t & 63) * 81 + k];
  float bv = bias[oc];
  for (int st = wv * 10; st < wv * 10 + 10; ++st) {
    int y = st >> 1, x0 = (st & 1) * 10;
    float acc[10];
#pragma unroll
    for (int i = 0; i < 10; ++i) acc[i] = bv;
#pragma unroll
    for (int ky = 0; ky < 9; ++ky) {
      const float* row = &sx[(y + ky) * 28 + x0];
      float rv[18];
#pragma unroll
      for (int i = 0; i < 18; ++i) rv[i] = row[i];
#pragma unroll
      for (int kx = 0; kx < 9; ++kx) {
        float wgt = wreg[ky * 9 + kx];
#pragma unroll
        for (int xi = 0; xi < 10; ++xi) acc[xi] = fmaf(rv[kx + xi], wgt, acc[xi]);
      }
    }
#pragma unroll
    for (int xi = 0; xi < 10; ++xi) {
      float av = fmaxf(acc[xi], 0.f);
      __hip_bfloat16 hi = __float2bfloat16(av);
      float lo = av - __bfloat162float(hi);
      size_t idx = ((size_t)(b_l * 400 + y * 20 + x0 + xi)) * 256 + oc;
      hT_hi[idx] = hi;
      hT_lo[idx] = __float2bfloat16(lo);
    }
  }
}

// ---- weight convert: prim_w[oc][ic][tap] f32 -> wt[tap][oc][ic] bf16 hi/lo ----
__global__ __launch_bounds__(256) void k_cvtw(const float* __restrict__ w,
    __hip_bfloat16* __restrict__ wt_hi, __hip_bfloat16* __restrict__ wt_lo) {
  int oc = blockIdx.x >> 2, icq = blockIdx.x & 3;
  __shared__ float sw[5184];
  int t = threadIdx.x;
  const float* src = w + ((size_t)oc * 256 + icq * 64) * 81;
  for (int i = t; i < 5184; i += 256) sw[i] = src[i];
  __syncthreads();
  for (int i = t; i < 5184; i += 256) {
    int tap = i >> 6, icl = i & 63;
    float v = sw[icl * 81 + tap];
    __hip_bfloat16 hi = __float2bfloat16(v);
    float lo = v - __bfloat162float(hi);
    size_t dst = (size_t)tap * 65536 + (size_t)oc * 256 + icq * 64 + icl;
    wt_hi[dst] = hi;
    wt_lo[dst] = __float2bfloat16(lo);
  }
}

// ---- primary caps conv as implicit GEMM, bf16 MFMA, 3-product hi/lo ----
// C[m=b_l*36+s][n=oc], K = 81 taps x 256 ic, split-K=3 over taps.
// Block: BM=128, BN=64, 4 waves (2x2 of 64m x 32n). K-step = 1 tap x 32 ic.
__global__ __launch_bounds__(256) void k_prim(
    const __hip_bfloat16* __restrict__ hT_hi, const __hip_bfloat16* __restrict__ hT_lo,
    const __hip_bfloat16* __restrict__ wt_hi, const __hip_bfloat16* __restrict__ wt_lo,
    float* __restrict__ pout) {
  int bid = blockIdx.x;
  int Nblk = bid & 3;
  int Mblk = (bid >> 2) % 36;
  int kb = bid / 144;
  int m0 = Mblk * 128, oc0 = Nblk * 64;
  __shared__ __align__(16) char lds[24576];  // Ah 8K | Al 8K | Bh 4K | Bl 4K
  int t = threadIdx.x, wv = t >> 6, lane = t & 63;
  int jswz = (t & 3) ^ ((t >> 2) & 3);
  int rA = t >> 2;
  size_t ro0, ro1;
  {
    int m = m0 + rA; int b = m / 36, s = m - b * 36, oy = s / 6, ox = s - oy * 6;
    ro0 = ((size_t)(b * 400 + oy * 40 + ox * 2)) * 512;
    m = m0 + rA + 64; b = m / 36; s = m - b * 36; oy = s / 6; ox = s - oy * 6;
    ro1 = ((size_t)(b * 400 + oy * 40 + ox * 2)) * 512;
  }
  const char* pAh = (const char*)hT_hi + jswz * 16;
  const char* pAl = (const char*)hT_lo + jswz * 16;
  size_t bo = ((size_t)(oc0 + rA)) * 512 + jswz * 16;
  const char* pBh = (const char*)wt_hi + bo;
  const char* pBl = (const char*)wt_lo + bo;
  char* dAh0 = lds + wv * 1024;
  char* dAh1 = lds + 4096 + wv * 1024;
  char* dAl0 = lds + 8192 + wv * 1024;
  char* dAl1 = lds + 12288 + wv * 1024;
  char* dBh  = lds + 16384 + wv * 1024;
  char* dBl  = lds + 20480 + wv * 1024;
  int wr = wv >> 1, wc = wv & 1;
  int swz16 = ((lane >> 4) ^ (lane & 3)) * 16;
  int arow[4], brow[2];
#pragma unroll
  for (int i = 0; i < 4; ++i) arow[i] = (wr * 64 + i * 16 + (lane & 15)) * 64 + swz16;
#pragma unroll
  for (int j = 0; j < 2; ++j) brow[j] = 16384 + (wc * 32 + j * 16 + (lane & 15)) * 64 + swz16;
  f32x4 acc[4][2];
#pragma unroll
  for (int i = 0; i < 4; ++i)
#pragma unroll
    for (int j = 0; j < 2; ++j) acc[i][j] = (f32x4){0.f, 0.f, 0.f, 0.f};

#pragma unroll 1
  for (int tt = 0; tt < 27; ++tt) {
    int tap = kb * 27 + tt;
    int ky = tap / 9, kx = tap - ky * 9;
    size_t offA = (size_t)(ky * 20 + kx) * 512;
    size_t offB = (size_t)tap * 131072;
#pragma unroll 1
    for (int icc = 0; icc < 8; ++icc) {
      size_t ko = (size_t)icc * 64;
      __syncthreads();
      gl16(pAh + ro0 + offA + ko, dAh0);
      gl16(pAh + ro1 + offA + ko, dAh1);
      gl16(pAl + ro0 + offA + ko, dAl0);
      gl16(pAl + ro1 + offA + ko, dAl1);
      gl16(pBh + offB + ko, dBh);
      gl16(pBl + offB + ko, dBl);
      __syncthreads();
      s16x8 ah[4], al[4], bh[2], bl[2];
#pragma unroll
      for (int i = 0; i < 4; ++i) {
        ah[i] = *(const s16x8*)(lds + arow[i]);
        al[i] = *(const s16x8*)(lds + 8192 + arow[i]);
      }
#pragma unroll
      for (int j = 0; j < 2; ++j) {
        bh[j] = *(const s16x8*)(lds + brow[j]);
        bl[j] = *(const s16x8*)(lds + 4096 + brow[j]);
      }
#pragma unroll
      for (int i = 0; i < 4; ++i)
#pragma unroll
        for (int j = 0; j < 2; ++j) {
          acc[i][j] = __builtin_amdgcn_mfma_f32_16x16x32_bf16(ah[i], bh[j], acc[i][j], 0, 0, 0);
          acc[i][j] = __builtin_amdgcn_mfma_f32_16x16x32_bf16(ah[i], bl[j], acc[i][j], 0, 0, 0);
          acc[i][j] = __builtin_amdgcn_mfma_f32_16x16x32_bf16(al[i], bh[j], acc[i][j], 0, 0, 0);
        }
    }
  }
  float* pb = pout + (size_t)kb * (4608 * 256);
#pragma unroll
  for (int i = 0; i < 4; ++i)
#pragma unroll
    for (int j = 0; j < 2; ++j) {
      int n = oc0 + wc * 32 + j * 16 + (lane & 15);
#pragma unroll
      for (int qq = 0; qq < 4; ++qq) {
        int m = m0 + wr * 64 + i * 16 + (lane >> 4) * 4 + qq;
        pb[(size_t)m * 256 + n] = acc[i][j][qq];
      }
    }
}

// ---- squash: 3 split-K partials + bias -> psT[b][i][r] (i-major) ----
__global__ __launch_bounds__(256) void k_squash2(const float* __restrict__ pout,
    const float* __restrict__ bias, float* __restrict__ psT, int b0) {
  int b_l = blockIdx.x;
  int t = threadIdx.x;
  __shared__ float buf[9216];
  __shared__ float sq[256];
  __shared__ float sc[32];
  float bv = bias[t];
  for (int s = 0; s < 36; ++s) {
    size_t base = ((size_t)(b_l * 36 + s)) * 256 + t;
    float val = pout[base] + pout[base + 1179648] + pout[base + 2359296] + bv;
    sq[t] = val * val;
    __syncthreads();
    if (t < 32) {
      float ss = 0.f;
#pragma unroll
      for (int i = 0; i < 8; ++i) ss += sq[t + i * 32];
      sc[t] = sqrtf(ss) / (1.f + ss);
    }
    __syncthreads();
    buf[t * 36 + s] = val * sc[t & 31];
    __syncthreads();
  }
  float* dst = psT + (size_t)(b0 + b_l) * 9216;
  for (int i = t; i < 9216; i += 256) dst[i] = buf[i];
}

// ---- fused routing: block = (class c, batch pair); rw read once per pair ----
__global__ __launch_bounds__(256) void k_route2(const float* __restrict__ psT,
    const float* __restrict__ rw, float* __restrict__ vout) {
  int c = blockIdx.x / 128;
  int bp0 = (blockIdx.x - c * 128) * 2;
  __shared__ float pri[2][16][NROUTE];   // 147.5 KB
  __shared__ float wred[4];
  __shared__ float red[64];
  __shared__ float vsq[2][16];
  __shared__ float sca[2];
  int tid = threadIdx.x, wv = tid >> 6;

  // priors for both batches; route_w slice read once
  for (int r = tid; r < NROUTE; r += 256) {
    float p8a[8], p8b[8];
#pragma unroll
    for (int i = 0; i < 8; ++i) {
      p8a[i] = psT[(size_t)bp0 * 9216 + i * 1152 + r];
      p8b[i] = psT[(size_t)(bp0 + 1) * 9216 + i * 1152 + r];
    }
    const float4* wp4 = (const float4*)&rw[((size_t)c * NROUTE + r) * 128];
    float pra[16], prb[16];
#pragma unroll
    for (int o = 0; o < 16; ++o) { pra[o] = 0.f; prb[o] = 0.f; }
#pragma unroll
    for (int i = 0; i < 8; ++i) {
      float av = p8a[i], bvv = p8b[i];
#pragma unroll
      for (int o4 = 0; o4 < 4; ++o4) {
        float4 w4 = wp4[i * 4 + o4];
        pra[o4 * 4 + 0] += av * w4.x; prb[o4 * 4 + 0] += bvv * w4.x;
        pra[o4 * 4 + 1] += av * w4.y; prb[o4 * 4 + 1] += bvv * w4.y;
        pra[o4 * 4 + 2] += av * w4.z; prb[o4 * 4 + 2] += bvv * w4.z;
        pra[o4 * 4 + 3] += av * w4.w; prb[o4 * 4 + 3] += bvv * w4.w;
      }
    }
#pragma unroll
    for (int o = 0; o < 16; ++o) {
      pri[0][o][r] = pra[o];
      pri[1][o][r] = prb[o];
    }
  }
  // logits in registers: r = tid + k*256, k=0..4
  float lgr[2][5];
#pragma unroll
  for (int h = 0; h < 2; ++h)
#pragma unroll
    for (int k = 0; k < 5; ++k) lgr[h][k] = 0.f;
  __syncthreads();

  for (int it = 0; it < 3; ++it) {
    for (int h = 0; h < 2; ++h) {
      // softmax over r
      float mx = -1e30f;
#pragma unroll
      for (int k = 0; k < 5; ++k) { int r = tid + k * 256; if (r < NROUTE) mx = fmaxf(mx, lgr[h][k]); }
#pragma unroll
      for (int off = 32; off; off >>= 1) mx = fmaxf(mx, __shfl_xor(mx, off));
      __syncthreads();
      if ((tid & 63) == 0) wred[wv] = mx;
      __syncthreads();
      mx = fmaxf(fmaxf(wred[0], wred[1]), fmaxf(wred[2], wred[3]));
      float er[5];
      float sm = 0.f;
#pragma unroll
      for (int k = 0; k < 5; ++k) {
        int r = tid + k * 256;
        er[k] = (r < NROUTE) ? expf(lgr[h][k] - mx) : 0.f;
        sm += er[k];
      }
#pragma unroll
      for (int off = 32; off; off >>= 1) sm += __shfl_xor(sm, off);
      __syncthreads();
      if ((tid & 63) == 0) wred[wv] = sm;
      __syncthreads();
      float inv = 1.f / (wred[0] + wred[1] + wred[2] + wred[3]);
      // outputs
      float a16[16];
#pragma unroll
      for (int o = 0; o < 16; ++o) a16[o] = 0.f;
#pragma unroll
      for (int k = 0; k < 5; ++k) {
        int r = tid + k * 256;
        if (r < NROUTE) {
          float pr_ = er[k] * inv;
#pragma unroll
          for (int o = 0; o < 16; ++o) a16[o] += pr_ * pri[h][o][r];
        }
      }
#pragma unroll
      for (int o = 0; o < 16; ++o)
#pragma unroll
        for (int off = 32; off; off >>= 1) a16[o] += __shfl_xor(a16[o], off);
      __syncthreads();
      if ((tid & 63) == 0) {
#pragma unroll
        for (int o = 0; o < 16; ++o) red[wv * 16 + o] = a16[o];
      }
      __syncthreads();
      if (tid < 16) {
        float s = red[tid] + red[16 + tid] + red[32 + tid] + red[48 + tid];
        red[tid] = s;
      }
      __syncthreads();
      if (tid == 0) {
        float sqs = 0.f;
        for (int o = 0; o < 16; ++o) sqs += red[o] * red[o];
        sca[h] = sqrtf(sqs) / (1.f + sqs);
      }
      __syncthreads();
      if (tid < 16) vsq[h][tid] = red[tid] * sca[h];
      __syncthreads();
      if (it < 2) {
#pragma unroll
        for (int k = 0; k < 5; ++k) {
          int r = tid + k * 256;
          if (r < NROUTE) {
            float d = 0.f;
#pragma unroll
            for (int o = 0; o < 16; ++o) d += pri[h][o][r] * vsq[h][o];
            lgr[h][k] += d;
          }
        }
      }
      __syncthreads();
    }
  }
  if (tid < 32) {
    int h = tid >> 4, o = tid & 15;
    vout[((size_t)c * BB + (bp0 + h)) * 16 + o] = vsq[h][o];
  }
}

// ---- classes + argmax one-hot mask ----
__global__ __launch_bounds__(64) void k_cls(const float* __restrict__ v,
                                            float* __restrict__ classes,
                                            float* __restrict__ masked) {
  int b = blockIdx.x;
  int t = threadIdx.x;
  __shared__ float snrm[10];
  __shared__ int samax;
  float vv[16];
  if (t < 10) {
    float sq = 0.f;
#pragma unroll
    for (int o = 0; o < 16; ++o) {
      float xx = v[(size_t)(t * BB + b) * 16 + o];
      vv[o] = xx;
      sq += xx * xx;
    }
    snrm[t] = sqrtf(sq);
  }
  __syncthreads();
  if (t == 0) {
    int am = 0;
    float bm = snrm[0];
    for (int cc = 1; cc < 10; ++cc)
      if (snrm[cc] > bm) { bm = snrm[cc]; am = cc; }
    samax = am;
  }
  __syncthreads();
  if (t < 10) {
    float mx = snrm[0];
    for (int cc = 1; cc < 10; ++cc) mx = fmaxf(mx, snrm[cc]);
    float sm = 0.f;
    for (int cc = 0; cc < 10; ++cc) sm += expf(snrm[cc] - mx);
    classes[b * 10 + t] = expf(snrm[t] - mx) / sm;
    float keep = (t == samax) ? 1.f : 0.f;
#pragma unroll
    for (int o = 0; o < 16; ++o)
      masked[(size_t)b * 160 + t * 16 + o] = vv[o] * keep;
  }
}

// ---- small FC GEMM ----
template <int ACT>
__global__ __launch_bounds__(256) void k_fc(const float* __restrict__ A,
                                            const float* __restrict__ W,
                                            const float* __restrict__ bias,
                                            float* __restrict__ O, int M, int N,
                                            int K) {
  int n0 = blockIdx.x * 64, m0 = blockIdx.y * 64;
  __shared__ float sa[64][17];
  __shared__ float sb[16][64];
  int tid = threadIdx.x, ty = tid >> 4, tx = tid & 15;
  float acc[4][4] = {};
  for (int k0 = 0; k0 < K; k0 += 16) {
    __syncthreads();
    for (int i = tid; i < 64 * 16; i += 256) {
      int m = i >> 4, k = i & 15;
      sa[m][k] = A[(size_t)(m0 + m) * K + k0 + k];
    }
    for (int i = tid; i < 16 * 64; i += 256) {
      int k = i >> 6, n = i & 63;
      int nn = n0 + n;
      sb[k][n] = (nn < N) ? W[(size_t)(k0 + k) * N + nn] : 0.f;
    }
    __syncthreads();
#pragma unroll
    for (int k = 0; k < 16; ++k) {
      float a0 = sa[ty * 4 + 0][k];
      float a1 = sa[ty * 4 + 1][k];
      float a2 = sa[ty * 4 + 2][k];
      float a3 = sa[ty * 4 + 3][k];
      float4 bv = *(const float4*)&sb[k][tx * 4];
      acc[0][0] += a0 * bv.x; acc[0][1] += a0 * bv.y; acc[0][2] += a0 * bv.z; acc[0][3] += a0 * bv.w;
      acc[1][0] += a1 * bv.x; acc[1][1] += a1 * bv.y; acc[1][2] += a1 * bv.z; acc[1][3] += a1 * bv.w;
      acc[2][0] += a2 * bv.x; acc[2][1] += a2 * bv.y; acc[2][2] += a2 * bv.z; acc[2][3] += a2 * bv.w;
      acc[3][0] += a3 * bv.x; acc[3][1] += a3 * bv.y; acc[3][2] += a3 * bv.z; acc[3][3] += a3 * bv.w;
    }
  }
#pragma unroll
  for (int i = 0; i < 4; ++i) {
    int m = m0 + ty * 4 + i;
#pragma unroll
    for (int j = 0; j < 4; ++j) {
      int n = n0 + tx * 4 + j;
      if (n < N) {
        float xv = acc[i][j] + bias[n];
        if (ACT == 0)
          xv = fmaxf(xv, 0.f);
        else
          xv = 1.f / (1.f + expf(-xv));
        O[(size_t)m * N + n] = xv;
      }
    }
  }
}

extern "C" void kernel_launch(void* const* d_in, const int* in_sizes, int n_in,
                              void* d_out, int out_size, void* d_ws,
                              size_t ws_size, hipStream_t stream) {
  (void)in_sizes; (void)n_in; (void)out_size; (void)ws_size;
  const float* x       = (const float*)d_in[0];
  const float* conv1_w = (const float*)d_in[1];
  const float* conv1_b = (const float*)d_in[2];
  const float* prim_w  = (const float*)d_in[3];
  const float* prim_b  = (const float*)d_in[4];
  const float* route_w = (const float*)d_in[5];
  const float* dec_w1  = (const float*)d_in[6];
  const float* dec_b1  = (const float*)d_in[7];
  const float* dec_w2  = (const float*)d_in[8];
  const float* dec_b2  = (const float*)d_in[9];
  const float* dec_w3  = (const float*)d_in[10];
  const float* dec_b3  = (const float*)d_in[11];
  float* out = (float*)d_out;

  char* wsb = (char*)d_ws;
  __hip_bfloat16* hT_hi = (__hip_bfloat16*)(wsb);                 // 26,214,400 B (half batch)
  __hip_bfloat16* hT_lo = (__hip_bfloat16*)(wsb + 26214400);      // 26,214,400 B
  __hip_bfloat16* wt_hi = (__hip_bfloat16*)(wsb + 52428800);      // 10,616,832 B
  __hip_bfloat16* wt_lo = (__hip_bfloat16*)(wsb + 63045632);      // 10,616,832 B
  float* pout = (float*)(wsb + 73662464);                         // 14,155,776 B (3 partials)
  float* psT  = (float*)(wsb + 87818240);                         //  9,437,184 B
  float* v    = (float*)(wsb + 97255424);
  float* mk   = (float*)(wsb + 97419264);
  float* h1   = (float*)(wsb + 97583104);
  float* h2   = (float*)(wsb + 98107392);

  k_cvtw<<<1024, 256, 0, stream>>>(prim_w, wt_hi, wt_lo);
  for (int hh = 0; hh < 2; ++hh) {
    int b0 = hh * 128;
    k_conv1b<<<512, 256, 0, stream>>>(x, conv1_w, conv1_b, hT_hi, hT_lo, b0);
    k_prim<<<432, 256, 0, stream>>>(hT_hi, hT_lo, wt_hi, wt_lo, pout);
    k_squash2<<<128, 256, 0, stream>>>(pout, prim_b, psT, b0);
  }
  k_route2<<<1280, 256, 0, stream>>>(psT, route_w, v);
  k_cls<<<256, 64, 0, stream>>>(v, out, mk);
  k_fc<0><<<dim3(8, 4), 256, 0, stream>>>(mk, dec_w1, dec_b1, h1, 256, 512, 160);
  k_fc<0><<<dim3(16, 4), 256, 0, stream>>>(h1, dec_w2, dec_b2, h2, 256, 1024, 512);
  k_fc<1><<<dim3(13, 4), 256, 0, stream>>>(h2, dec_w3, dec_b3, out + 2560, 256, 784, 1024);
}